// Round 14
// baseline (314.963 us; speedup 1.0000x reference)
//
#include <hip/hip_runtime.h>
#include <type_traits>

typedef unsigned short ushort;
typedef unsigned int uint;
typedef __bf16 bf16x8 __attribute__((ext_vector_type(8)));
typedef unsigned short ushort8v __attribute__((ext_vector_type(8)));
typedef float f32x4 __attribute__((ext_vector_type(4)));

__device__ __forceinline__ float b2f(ushort u) {
    unsigned int x = ((unsigned int)u) << 16;
    float f;
    __builtin_memcpy(&f, &x, 4);
    return f;
}
__device__ __forceinline__ ushort f2bf(float f) {
    unsigned int x;
    __builtin_memcpy(&x, &f, 4);
    unsigned int r = x + 0x7fffu + ((x >> 16) & 1u);
    return (ushort)(r >> 16);
}
__device__ __forceinline__ float u2f_lo(uint u) {
    uint x = u << 16;
    float f;
    __builtin_memcpy(&f, &x, 4);
    return f;
}
__device__ __forceinline__ float u2f_hi(uint u) {
    uint x = u & 0xffff0000u;
    float f;
    __builtin_memcpy(&f, &x, 4);
    return f;
}
__device__ __forceinline__ uint packbf(float a, float b) {
    return (uint)f2bf(a) | ((uint)f2bf(b) << 16);
}

#define NPIX 16384  // H*W = 128*128
#define PSTRIDE 136 // padded plane row stride (ushorts); 68 uints

// Channel-major tiled layout: [b][tile(256)][ch(CH)][64 px]
__device__ __forceinline__ size_t tadr(int b, int CH, int tile, int ch, int off) {
    return (((size_t)b * 256 + tile) * CH + ch) * 64 + off;
}
// Pixel-major tiled layout for x2: [b][tile(256)][px(64)][ch(128)]
__device__ __forceinline__ size_t padr(int b, int tile, int p, int c) {
    return (((size_t)b * 256 + tile) * 64 + p) * 128 + c;
}
// px-grouped gated layout: [b][tile(256)][pxq(4)][ch(512)][pxl(16)]
__device__ __forceinline__ size_t gadr(int b, int tile, int pxq, int ch, int pxl) {
    return ((((size_t)b * 256 + tile) * 4 + pxq) * 512 + ch) * 16 + pxl;
}

// ---------------------------------------------------------------------------
// stage one 128x128 plane (channel c of ch-major tiled tensor) into padded LDS.
// ---------------------------------------------------------------------------
__device__ __forceinline__ void stage_plane(ushort* pl, const ushort* __restrict__ src,
                                            int b, int c, int CH, int tid) {
    uint* plu = (uint*)pl;
    for (int i = tid; i < 784; i += 256) {
        int idx;
        if (i < 136) idx = i;                       // rows 0-1
        else if (i < 272) idx = 8840 + (i - 136);   // rows 130-131
        else {
            int j = i - 272;
            int r = (j >> 2) + 2;                   // rows 2..129
            int cs = j & 3;
            idx = r * 68 + (cs == 0 ? 0 : 64 + cs); // uint 0 (left pad), 65-67 (right pad)
        }
        plu[idx] = 0u;
    }
    for (int i = tid; i < 2048; i += 256) {
        int row = i >> 4, xg = (i & 15) << 3;
        int px0 = row * 128 + xg;
        uint4 v = *(const uint4*)&src[tadr(b, CH, px0 >> 6, c, px0 & 63)];
        uint* dst = (uint*)&pl[(row + 2) * PSTRIDE + xg + 2];
        dst[0] = v.x; dst[1] = v.y; dst[2] = v.z; dst[3] = v.w;
    }
    __syncthreads();
}

// unpack 12 consecutive bf16 at rowp (16B-aligned) into f32
__device__ __forceinline__ void unpack12(const ushort* rowp, float* cc) {
    const uint* rp = (const uint*)rowp;
    uint4 u = *(const uint4*)rp;
    uint2 v = *(const uint2*)(rp + 4);
    cc[0] = u2f_lo(u.x); cc[1] = u2f_hi(u.x);
    cc[2] = u2f_lo(u.y); cc[3] = u2f_hi(u.y);
    cc[4] = u2f_lo(u.z); cc[5] = u2f_hi(u.z);
    cc[6] = u2f_lo(u.w); cc[7] = u2f_hi(u.w);
    cc[8] = u2f_lo(v.x); cc[9] = u2f_hi(v.x);
    cc[10] = u2f_lo(v.y); cc[11] = u2f_hi(v.y);
}

// ---------------------------------------------------------------------------
// K0: convert fp32 weights to bf16 once (qkv_w, pin_w, pout_w).
// ---------------------------------------------------------------------------
__global__ __launch_bounds__(256) void wcvt(const float* __restrict__ s0, ushort* __restrict__ d0, int n0,
                                            const float* __restrict__ s1, ushort* __restrict__ d1, int n1,
                                            const float* __restrict__ s2, ushort* __restrict__ d2, int n2) {
    int i = blockIdx.x * 256 + threadIdx.x;
    if (i < n0) d0[i] = f2bf(s0[i]);
    else if (i < n0 + n1) d1[i - n0] = f2bf(s1[i - n0]);
    else if (i < n0 + n1 + n2) d2[i - n0 - n1] = f2bf(s2[i - n0 - n1]);
}

// ---------------------------------------------------------------------------
// K1: fused LayerNorm(C=128) + qkv 1x1 conv via MFMA (R12 structure).
// ---------------------------------------------------------------------------
template <int O>
__global__ __launch_bounds__(256) void ln_gemm_mfma(const float* __restrict__ xin,
                                                    const ushort* __restrict__ Wb,
                                                    const float* __restrict__ gamma,
                                                    const float* __restrict__ beta,
                                                    ushort* __restrict__ out) {
    __shared__ ushort xs[64][136];
    __shared__ float red[2][4][64];
    __shared__ float mu[64], rs[64];
    __shared__ float gl[128], bl[128];

    const int blk = blockIdx.x;
    const int b = blk >> 8;
    const int tile = blk & 255;
    const int tid = threadIdx.x;

    const float* xb = xin + (size_t)b * 128 * NPIX + tile * 64;
    float vx[4][8];
#pragma unroll
    for (int k = 0; k < 4; k++) {
        int i = tid + k * 256;
        int p = i & 63, cg = i >> 6;
        const float* src = xb + (size_t)(cg * 8) * NPIX + p;
#pragma unroll
        for (int j = 0; j < 8; j++) vx[k][j] = src[(size_t)j * NPIX];
    }
    if (tid < 128) {
        gl[tid] = gamma[tid];
        bl[tid] = beta[tid];
    }
#pragma unroll
    for (int k = 0; k < 4; k++) {
        int i = tid + k * 256;
        int p = i & 63, cg = i >> 6;
        ushort8v u;
#pragma unroll
        for (int j = 0; j < 8; j++) u[j] = f2bf(vx[k][j]);
        *(ushort8v*)&xs[p][cg * 8] = u;
    }
    __syncthreads();

    {
        const int p = tid & 63, part = tid >> 6;
        float s = 0.f, ss = 0.f;
#pragma unroll
        for (int q = 0; q < 4; q++) {
            ushort8v u = *(const ushort8v*)&xs[p][part * 32 + q * 8];
#pragma unroll
            for (int j = 0; j < 8; j++) {
                float v = b2f(u[j]);
                s += v;
                ss += v * v;
            }
        }
        red[0][part][p] = s;
        red[1][part][p] = ss;
    }
    __syncthreads();
    if (tid < 64) {
        float s = red[0][0][tid] + red[0][1][tid] + red[0][2][tid] + red[0][3][tid];
        float ss = red[1][0][tid] + red[1][1][tid] + red[1][2][tid] + red[1][3][tid];
        float m = s * (1.f / 128.f);
        float var = ss * (1.f / 128.f) - m * m;
        mu[tid] = m;
        rs[tid] = rsqrtf(var + 1e-5f);
    }
    __syncthreads();
    {
        const int p = tid & 63, part = tid >> 6;
        const float mp = mu[p], rp = rs[p];
#pragma unroll
        for (int q = 0; q < 4; q++) {
            int c0 = part * 32 + q * 8;
            ushort8v u = *(const ushort8v*)&xs[p][c0];
            ushort8v o;
#pragma unroll
            for (int j = 0; j < 8; j++) {
                float v = b2f(u[j]);
                o[j] = f2bf((v - mp) * rp * gl[c0 + j] + bl[c0 + j]);
            }
            *(ushort8v*)&xs[p][c0] = o;
        }
    }
    __syncthreads();

    const int wv = tid >> 6, lane = tid & 63;
    const int lr = lane & 15, lg = lane >> 4;

    bf16x8 bfr[4][4];
#pragma unroll
    for (int t = 0; t < 4; t++)
#pragma unroll
        for (int kc = 0; kc < 4; kc++)
            bfr[t][kc] = __builtin_bit_cast(bf16x8, *(const ushort8v*)&xs[t * 16 + lr][kc * 32 + lg * 8]);

    constexpr int MT = O / 64;
    bf16x8 afp[2][4];
#pragma unroll
    for (int kc = 0; kc < 4; kc++)
        afp[0][kc] = __builtin_bit_cast(bf16x8,
            *(const ushort8v*)&Wb[(size_t)(wv * 16 + lr) * 128 + kc * 32 + lg * 8]);

    f32x4 accPair[2][4];
    const int px8 = tid & 7, cb = tid >> 3;
    ushort* outp = out + tadr(b, O, tile, 0, 0);

#pragma unroll
    for (int mt = 0; mt < MT; mt++) {
        if (mt + 1 < MT) {
            const int o0n = ((mt + 1) * 4 + wv) * 16;
#pragma unroll
            for (int kc = 0; kc < 4; kc++)
                afp[(mt + 1) & 1][kc] = __builtin_bit_cast(bf16x8,
                    *(const ushort8v*)&Wb[(size_t)(o0n + lr) * 128 + kc * 32 + lg * 8]);
        }
        f32x4* acc = accPair[mt & 1];
#pragma unroll
        for (int t = 0; t < 4; t++) acc[t] = (f32x4){0.f, 0.f, 0.f, 0.f};
#pragma unroll
        for (int kc = 0; kc < 4; kc++)
#pragma unroll
            for (int t = 0; t < 4; t++)
                acc[t] = __builtin_amdgcn_mfma_f32_16x16x32_bf16(afp[mt & 1][kc], bfr[t][kc], acc[t], 0, 0, 0);

        if (mt & 1) {
            __syncthreads();
#pragma unroll
            for (int h = 0; h < 2; h++) {
                const int lc = h * 64 + wv * 16 + lg * 4;
#pragma unroll
                for (int t = 0; t < 4; t++) {
                    int px = t * 16 + lr;
                    uint2 pk;
                    pk.x = packbf(accPair[h][t][0], accPair[h][t][1]);
                    pk.y = packbf(accPair[h][t][2], accPair[h][t][3]);
                    *(uint2*)&xs[px][lc] = pk;
                }
            }
            __syncthreads();
            const int pairbase = (mt >> 1) * 128;
#pragma unroll
            for (int cc = 0; cc < 4; cc++) {
                int c = cb + cc * 32;
                ushort8v u;
#pragma unroll
                for (int j = 0; j < 8; j++) u[j] = xs[px8 * 8 + j][c];
                *(ushort8v*)&outp[(size_t)(pairbase + c) * 64 + px8 * 8] = u;
            }
        }
    }
}

// ---------------------------------------------------------------------------
// K2: 3x3 depthwise conv, one (b,c) plane per block; ch-major tiled in/out.
// ---------------------------------------------------------------------------
__global__ __launch_bounds__(256) void dwconv3_lds(const ushort* __restrict__ in,
                                                   const float* __restrict__ wdw,
                                                   ushort* __restrict__ out, int CH) {
    __shared__ ushort pl[132 * PSTRIDE];
    const int c = blockIdx.x;
    const int b = blockIdx.y;
    const int tid = threadIdx.x;

    float w[9];
#pragma unroll
    for (int j = 0; j < 9; j++) w[j] = wdw[c * 9 + j];

    stage_plane(pl, in, b, c, CH, tid);

    const int x = (tid & 15) * 8;
    const int ybase = tid >> 4;
#pragma unroll 1
    for (int k = 0; k < 8; k++) {
        const int y = k * 16 + ybase;
        float a[8];
#pragma unroll
        for (int p = 0; p < 8; p++) a[p] = 0.f;
#pragma unroll
        for (int ky = 0; ky < 3; ky++) {
            float cc[12];
            unpack12(&pl[(y + ky + 1) * PSTRIDE + x], cc);
#pragma unroll
            for (int kx = 0; kx < 3; kx++) {
                float wv = w[ky * 3 + kx];
#pragma unroll
                for (int p = 0; p < 8; p++) a[p] += cc[p + kx + 1] * wv;
            }
        }
        const int px0 = (y << 7) + x;
        uint4 o;
        o.x = packbf(a[0], a[1]);
        o.y = packbf(a[2], a[3]);
        o.z = packbf(a[4], a[5]);
        o.w = packbf(a[6], a[7]);
        *(uint4*)&out[tadr(b, CH, px0 >> 6, c, px0 & 63)] = o;
    }
}

// ---------------------------------------------------------------------------
// K6/K7/gating fused. Output now px-grouped gated layout (gadr); the two
// uint4 stores per iteration are unchanged in width, only readdressed.
// ---------------------------------------------------------------------------
__global__ __launch_bounds__(256) void dw_gated(const ushort* __restrict__ t,
                                                const float* __restrict__ w3_,
                                                const float* __restrict__ w5_,
                                                const float* __restrict__ c1w,
                                                ushort* __restrict__ gated) {
    __shared__ ushort pl[132 * PSTRIDE];
    const int c = blockIdx.x;
    const int b = blockIdx.y;
    const int tid = threadIdx.x;

    float w3[9], w5[25];
#pragma unroll
    for (int j = 0; j < 9; j++) w3[j] = w3_[c * 9 + j];
#pragma unroll
    for (int j = 0; j < 25; j++) w5[j] = w5_[c * 25 + j];
    const float c1v = c1w[c];

    stage_plane(pl, t, b, c, 256, tid);

    const int x = (tid & 15) * 8;
    const int ybase = tid >> 4;
#pragma unroll 1
    for (int k = 0; k < 8; k++) {
        const int y = k * 16 + ybase;
        float a5[8], a3[8], tc[8];
#pragma unroll
        for (int p = 0; p < 8; p++) { a5[p] = 0.f; a3[p] = 0.f; }
#pragma unroll
        for (int ky = 0; ky < 5; ky++) {
            float cc[12];
            unpack12(&pl[(y + ky) * PSTRIDE + x], cc);
#pragma unroll
            for (int kx = 0; kx < 5; kx++) {
                float wv = w5[ky * 5 + kx];
#pragma unroll
                for (int p = 0; p < 8; p++) a5[p] += cc[p + kx] * wv;
            }
            if (ky >= 1 && ky <= 3) {
#pragma unroll
                for (int kx = 0; kx < 3; kx++) {
                    float wv = w3[(ky - 1) * 3 + kx];
#pragma unroll
                    for (int p = 0; p < 8; p++) a3[p] += cc[p + kx + 1] * wv;
                }
            }
            if (ky == 2) {
#pragma unroll
                for (int p = 0; p < 8; p++) tc[p] = cc[p + 2];
            }
        }
        const int px0 = (y << 7) + x;
        uint4 o3, o5;
        float g[8];
#pragma unroll
        for (int p = 0; p < 8; p++) {
            float x1 = tc[p] * c1v;
            g[p] = x1 * __builtin_amdgcn_rcpf(1.f + __expf(-1.702f * x1));
        }
        o3.x = packbf(g[0] * a3[0], g[1] * a3[1]);
        o3.y = packbf(g[2] * a3[2], g[3] * a3[3]);
        o3.z = packbf(g[4] * a3[4], g[5] * a3[5]);
        o3.w = packbf(g[6] * a3[6], g[7] * a3[7]);
        o5.x = packbf(g[0] * a5[0], g[1] * a5[1]);
        o5.y = packbf(g[2] * a5[2], g[3] * a5[3]);
        o5.z = packbf(g[4] * a5[4], g[5] * a5[5]);
        o5.w = packbf(g[6] * a5[6], g[7] * a5[7]);
        const int tl = px0 >> 6, pxq = (px0 >> 4) & 3, pxl = px0 & 15;
        *(uint4*)&gated[gadr(b, tl, pxq, c, pxl)] = o3;
        *(uint4*)&gated[gadr(b, tl, pxq, 256 + c, pxl)] = o5;
    }
}

// ---------------------------------------------------------------------------
// K3: per (b,h) attention -> M (unchanged from R13).
// ---------------------------------------------------------------------------
__global__ __launch_bounds__(512) void attn_M(const ushort* __restrict__ qkv,
                                              const float* __restrict__ temp,
                                              const float* __restrict__ attn_proj,
                                              ushort* __restrict__ M) {
    __shared__ float Sp[8][16][16];
    __shared__ float QSS[8][16], KSS[8][16];
    __shared__ float A[16][17];

    const int bh = blockIdx.x, b = bh >> 3, h = bh & 7;
    const int tid = threadIdx.x;
    const int w = tid >> 6, lane = tid & 63;
    const int lr = lane & 15, lg = lane >> 4;

    const size_t qbase = (((size_t)b * 256 + w * 32) * 384 + h * 16 + lr) * 64 + lg * 8;
    const size_t kbase = qbase + (size_t)128 * 64;

    f32x4 acc = {0.f, 0.f, 0.f, 0.f};
    f32x4 accq = {0.f, 0.f, 0.f, 0.f};
    f32x4 acck = {0.f, 0.f, 0.f, 0.f};
#pragma unroll 2
    for (int it = 0; it < 64; it++) {
        size_t off = (size_t)(it >> 1) * (384 * 64) + (it & 1) * 32;
        bf16x8 qf = __builtin_bit_cast(bf16x8, *(const ushort8v*)(qkv + qbase + off));
        bf16x8 kf = __builtin_bit_cast(bf16x8, *(const ushort8v*)(qkv + kbase + off));
        acc = __builtin_amdgcn_mfma_f32_16x16x32_bf16(qf, kf, acc, 0, 0, 0);
        accq = __builtin_amdgcn_mfma_f32_16x16x32_bf16(qf, qf, accq, 0, 0, 0);
        acck = __builtin_amdgcn_mfma_f32_16x16x32_bf16(kf, kf, acck, 0, 0, 0);
    }
#pragma unroll
    for (int r = 0; r < 4; r++) Sp[w][lg * 4 + r][lr] = acc[r];
    if (lg == (lr >> 2)) {
        QSS[w][lr] = accq[lr & 3];
        KSS[w][lr] = acck[lr & 3];
    }
    __syncthreads();

    if (tid < 256) {
        const int d = tid >> 4, e = tid & 15;
        float S = 0.f, q2 = 0.f, k2 = 0.f;
#pragma unroll
        for (int s = 0; s < 8; s++) {
            S += Sp[s][d][e];
            q2 += QSS[s][d];
            k2 += KSS[s][e];
        }
        float nq = fmaxf(sqrtf(q2), 1e-12f);
        float nk = fmaxf(sqrtf(k2), 1e-12f);
        float logit = S / (nq * nk) * temp[h];
        float m = logit;
        for (int off = 8; off; off >>= 1) m = fmaxf(m, __shfl_xor(m, off, 64));
        float ex = expf(logit - m);
        float sum = ex;
        for (int off = 8; off; off >>= 1) sum += __shfl_xor(sum, off, 64);
        A[d][e] = ex / sum;
    }
    __syncthreads();

    for (int i = tid; i < 2048; i += 512) {
        int o = i >> 4, ee = i & 15;
        float acc2 = 0.f;
#pragma unroll
        for (int dd = 0; dd < 16; dd++) acc2 += attn_proj[o * 128 + h * 16 + dd] * A[dd][ee];
        M[((size_t)b * 128 + o) * 128 + h * 16 + ee] = f2bf(acc2);
    }
}

// ---------------------------------------------------------------------------
// K4+K5 FUSED: x2 = x + M_b @ v, then t = pin @ LN2(x2) (unchanged from R13).
// ---------------------------------------------------------------------------
__global__ __launch_bounds__(256) void mv_ln_mfma(const ushort* __restrict__ qkv,
                                                  const ushort* __restrict__ Mb16,
                                                  const float* __restrict__ x,
                                                  const ushort* __restrict__ pin_b,
                                                  const float* __restrict__ gamma,
                                                  const float* __restrict__ beta,
                                                  ushort* __restrict__ x2,
                                                  ushort* __restrict__ t_out) {
    __shared__ ushort ts[64][136];
    __shared__ float red[2][4][64];
    __shared__ float mu[64], rs[64];
    __shared__ float gl[128], bl[128];

    const int blk = blockIdx.x;
    const int b = blk >> 8;
    const int tile = blk & 255;
    const int tid = threadIdx.x;
    const int wv = tid >> 6, lane = tid & 63;
    const int lr = lane & 15, lg = lane >> 4;

    const ushort* Mb = Mb16 + (size_t)b * 128 * 128;
    bf16x8 mfr[2][4];
#pragma unroll
    for (int mt = 0; mt < 2; mt++)
#pragma unroll
        for (int kc = 0; kc < 4; kc++)
            mfr[mt][kc] = __builtin_bit_cast(bf16x8,
                *(const ushort8v*)&Mb[(size_t)((wv * 2 + mt) * 16 + lr) * 128 + kc * 32 + lg * 8]);

    const ushort* vb = qkv + tadr(b, 384, tile, 256, 0);
    ushort8v vv[4];
#pragma unroll
    for (int k = 0; k < 4; k++) {
        int idx = tid + k * 256;
        int c = idx & 127, pg = idx >> 7;
        vv[k] = *(const ushort8v*)&vb[c * 64 + pg * 8];
    }
    if (tid < 128) {
        gl[tid] = gamma[tid];
        bl[tid] = beta[tid];
    }
#pragma unroll
    for (int k = 0; k < 4; k++) {
        int idx = tid + k * 256;
        int c = idx & 127, pg = idx >> 7;
#pragma unroll
        for (int j = 0; j < 8; j++) ts[pg * 8 + j][c] = vv[k][j];
    }
    __syncthreads();

    bf16x8 bfr[4][4];
#pragma unroll
    for (int t = 0; t < 4; t++)
#pragma unroll
        for (int kc = 0; kc < 4; kc++)
            bfr[t][kc] = __builtin_bit_cast(bf16x8, *(const ushort8v*)&ts[t * 16 + lr][kc * 32 + lg * 8]);
    __syncthreads();

#pragma unroll
    for (int mt = 0; mt < 2; mt++) {
        const int o0 = (wv * 2 + mt) * 16;
        f32x4 acc[4] = {{0.f, 0.f, 0.f, 0.f}, {0.f, 0.f, 0.f, 0.f}, {0.f, 0.f, 0.f, 0.f}, {0.f, 0.f, 0.f, 0.f}};
#pragma unroll
        for (int kc = 0; kc < 4; kc++)
#pragma unroll
            for (int t = 0; t < 4; t++)
                acc[t] = __builtin_amdgcn_mfma_f32_16x16x32_bf16(mfr[mt][kc], bfr[t][kc], acc[t], 0, 0, 0);
#pragma unroll
        for (int t = 0; t < 4; t++) {
            int px = t * 16 + lr;
            const float* xp = &x[((size_t)b * 128 + o0 + lg * 4) * NPIX + tile * 64 + px];
            uint2 pk;
            pk.x = packbf(xp[0] + acc[t][0], xp[NPIX] + acc[t][1]);
            pk.y = packbf(xp[2 * NPIX] + acc[t][2], xp[3 * NPIX] + acc[t][3]);
            *(uint2*)&ts[px][o0 + lg * 4] = pk;
        }
    }

    bf16x8 pfp[2][4];
#pragma unroll
    for (int kc = 0; kc < 4; kc++)
        pfp[0][kc] = __builtin_bit_cast(bf16x8,
            *(const ushort8v*)&pin_b[(size_t)(wv * 16 + lr) * 128 + kc * 32 + lg * 8]);
    __syncthreads();

#pragma unroll
    for (int k = 0; k < 4; k++) {
        int idx = tid + k * 256;
        int p = idx >> 4, seg = idx & 15;
        uint4 v = *(const uint4*)&ts[p][seg * 8];
        *(uint4*)&x2[padr(b, tile, p, seg * 8)] = v;
    }
    {
        const int p = tid & 63, part = tid >> 6;
        float s = 0.f, ss = 0.f;
#pragma unroll
        for (int q = 0; q < 4; q++) {
            ushort8v u = *(const ushort8v*)&ts[p][part * 32 + q * 8];
#pragma unroll
            for (int j = 0; j < 8; j++) {
                float v = b2f(u[j]);
                s += v;
                ss += v * v;
            }
        }
        red[0][part][p] = s;
        red[1][part][p] = ss;
    }
    __syncthreads();
    if (tid < 64) {
        float s = red[0][0][tid] + red[0][1][tid] + red[0][2][tid] + red[0][3][tid];
        float ss = red[1][0][tid] + red[1][1][tid] + red[1][2][tid] + red[1][3][tid];
        float m = s * (1.f / 128.f);
        float var = ss * (1.f / 128.f) - m * m;
        mu[tid] = m;
        rs[tid] = rsqrtf(var + 1e-5f);
    }
    __syncthreads();
    {
        const int p = tid & 63, part = tid >> 6;
        const float mp = mu[p], rp = rs[p];
#pragma unroll
        for (int q = 0; q < 4; q++) {
            int c0 = part * 32 + q * 8;
            ushort8v u = *(const ushort8v*)&ts[p][c0];
            ushort8v o;
#pragma unroll
            for (int j = 0; j < 8; j++) {
                float v = b2f(u[j]);
                o[j] = f2bf((v - mp) * rp * gl[c0 + j] + bl[c0 + j]);
            }
            *(ushort8v*)&ts[p][c0] = o;
        }
    }
    __syncthreads();

    bf16x8 bfr2[4][4];
#pragma unroll
    for (int t = 0; t < 4; t++)
#pragma unroll
        for (int kc = 0; kc < 4; kc++)
            bfr2[t][kc] = __builtin_bit_cast(bf16x8, *(const ushort8v*)&ts[t * 16 + lr][kc * 32 + lg * 8]);

    f32x4 accPair[2][4];
    const int px8 = tid & 7, cb = tid >> 3;
    ushort* toutp = t_out + tadr(b, 256, tile, 0, 0);

#pragma unroll
    for (int mt = 0; mt < 4; mt++) {
        if (mt + 1 < 4) {
            const int o0n = ((mt + 1) * 4 + wv) * 16;
#pragma unroll
            for (int kc = 0; kc < 4; kc++)
                pfp[(mt + 1) & 1][kc] = __builtin_bit_cast(bf16x8,
                    *(const ushort8v*)&pin_b[(size_t)(o0n + lr) * 128 + kc * 32 + lg * 8]);
        }
        f32x4* acc = accPair[mt & 1];
#pragma unroll
        for (int t = 0; t < 4; t++) acc[t] = (f32x4){0.f, 0.f, 0.f, 0.f};
#pragma unroll
        for (int kc = 0; kc < 4; kc++)
#pragma unroll
            for (int t = 0; t < 4; t++)
                acc[t] = __builtin_amdgcn_mfma_f32_16x16x32_bf16(pfp[mt & 1][kc], bfr2[t][kc], acc[t], 0, 0, 0);

        if (mt & 1) {
            __syncthreads();
#pragma unroll
            for (int h = 0; h < 2; h++) {
                const int lc = h * 64 + wv * 16 + lg * 4;
#pragma unroll
                for (int t = 0; t < 4; t++) {
                    int px = t * 16 + lr;
                    uint2 pk;
                    pk.x = packbf(accPair[h][t][0], accPair[h][t][1]);
                    pk.y = packbf(accPair[h][t][2], accPair[h][t][3]);
                    *(uint2*)&ts[px][lc] = pk;
                }
            }
            __syncthreads();
            const int pairbase = (mt >> 1) * 128;
#pragma unroll
            for (int cc = 0; cc < 4; cc++) {
                int c = cb + cc * 32;
                ushort8v u;
#pragma unroll
                for (int j = 0; j < 8; j++) u[j] = ts[px8 * 8 + j][c];
                *(ushort8v*)&toutp[(size_t)(pairbase + c) * 64 + px8 * 8] = u;
            }
        }
    }
}

// ---------------------------------------------------------------------------
// K8: out = x2 + pout[128,512] @ gated via MFMA.
// gated is px-grouped [pxq][512][16]; staging is a straight 8KB memcpy
// (16B loads + 16B ds_writes, T14 issue-early/write-late); B-fragments via
// ds_read_b64_tr_b16 hardware transpose reads (T10). f32 repack epilogue.
// ---------------------------------------------------------------------------
__global__ __launch_bounds__(256) void gdfn_mfma(const ushort* __restrict__ gated,
                                                 const ushort* __restrict__ x2,
                                                 const ushort* __restrict__ pout_b,
                                                 float* __restrict__ out) {
    __shared__ union {
        ushort gs[2][4096];   // 16384 B: dbuf chunk, [pxq(4)][cc(64)][pxl(16)]
        float xf[32][129];    // 16512 B: f32 repack (used after K-loop)
    } sm;

    const int blk = blockIdx.x;
    const int b = blk >> 8;
    const int tile = blk & 255;
    const int tid = threadIdx.x;
    const int wv = tid >> 6, lane = tid & 63;
    const int lr = lane & 15, lg = lane >> 4;

    const ushort* gb = gated + gadr(b, tile, 0, 0, 0);
    const int spxq = tid >> 6, scc = tid & 63;                // staging mapping
    const size_t sgoff = (size_t)spxq * 8192 + scc * 16;      // + kb*1024

    // per-lane tr-read base (bytes): [pxq][cc][pxl] -> tt*2048 + k*32 + pxl*2
    const uint lbase = (uint)(uintptr_t)&sm.gs[0][0] + lg * 256 + lr * 2;

    f32x4 acc[2][4];
#pragma unroll
    for (int mt = 0; mt < 2; mt++)
#pragma unroll
        for (int tt = 0; tt < 4; tt++) acc[mt][tt] = (f32x4){0.f, 0.f, 0.f, 0.f};

    // prologue: stage chunk 0 into buf 0
    {
        uint4 a0 = *(const uint4*)&gb[sgoff];
        uint4 a1 = *(const uint4*)&gb[sgoff + 8];
        *(uint4*)&sm.gs[0][tid * 16] = a0;
        *(uint4*)&sm.gs[0][tid * 16 + 8] = a1;
    }
    __syncthreads();

#pragma unroll
    for (int kb = 0; kb < 8; kb++) {
        const int cur = kb & 1;

        // T14 issue-early: next chunk's wide loads
        uint4 nA, nB;
        if (kb < 7) {
            nA = *(const uint4*)&gb[sgoff + (kb + 1) * 1024];
            nB = *(const uint4*)&gb[sgoff + (kb + 1) * 1024 + 8];
        }

        // B-fragments via hardware transpose reads from sm.gs[cur]
        bf16x8 bfrg[4][2];
        {
            const uint la = lbase + cur * 8192;
#pragma unroll
            for (int tt = 0; tt < 4; tt++)
#pragma unroll
                for (int kc = 0; kc < 2; kc++) {
                    uint2 r0, r1;
                    asm volatile("ds_read_b64_tr_b16 %0, %2 offset:%3\n\t"
                                 "ds_read_b64_tr_b16 %1, %2 offset:%4"
                                 : "=&v"(r0), "=&v"(r1)
                                 : "v"(la), "i"(tt * 2048 + kc * 1024), "i"(tt * 2048 + kc * 1024 + 128));
                    uint4 q;
                    q.x = r0.x; q.y = r0.y; q.z = r1.x; q.w = r1.y;
                    bfrg[tt][kc] = __builtin_bit_cast(bf16x8, q);
                }
        }
        asm volatile("s_waitcnt lgkmcnt(0)" ::: "memory");
        __builtin_amdgcn_sched_barrier(0);

#pragma unroll
        for (int mt = 0; mt < 2; mt++) {
            const int o0 = (wv * 2 + mt) * 16;
            bf16x8 afr[2];
#pragma unroll
            for (int kc = 0; kc < 2; kc++)
                afr[kc] = __builtin_bit_cast(bf16x8,
                    *(const ushort8v*)&pout_b[(size_t)(o0 + lr) * 512 + kb * 64 + kc * 32 + lg * 8]);
#pragma unroll
            for (int kc = 0; kc < 2; kc++)
#pragma unroll
                for (int tt = 0; tt < 4; tt++)
                    acc[mt][tt] = __builtin_amdgcn_mfma_f32_16x16x32_bf16(afr[kc], bfrg[tt][kc], acc[mt][tt], 0, 0, 0);
        }

        // T14 write-late: publish next chunk
        if (kb < 7) {
            *(uint4*)&sm.gs[cur ^ 1][tid * 16] = nA;
            *(uint4*)&sm.gs[cur ^ 1][tid * 16 + 8] = nB;
        }
        __syncthreads();
    }

    // epilogue: add x2, repack via xf[32][129] in two 32-px halves
#pragma unroll
    for (int h = 0; h < 2; h++) {
#pragma unroll
        for (int mt = 0; mt < 2; mt++)
#pragma unroll
            for (int t2 = 0; t2 < 2; t2++) {
                const int tt = h * 2 + t2;
                int o0 = (wv * 2 + mt) * 16 + lg * 4;
                int px = tt * 16 + lr;
                uint2 xw = *(const uint2*)&x2[padr(b, tile, px, o0)];
                sm.xf[px - h * 32][o0 + 0] = u2f_lo(xw.x) + acc[mt][tt][0];
                sm.xf[px - h * 32][o0 + 1] = u2f_hi(xw.x) + acc[mt][tt][1];
                sm.xf[px - h * 32][o0 + 2] = u2f_lo(xw.y) + acc[mt][tt][2];
                sm.xf[px - h * 32][o0 + 3] = u2f_hi(xw.y) + acc[mt][tt][3];
            }
        __syncthreads();
        {
            const int qx = tid & 7;
            const int cbase = tid >> 3;
#pragma unroll
            for (int cc = 0; cc < 4; cc++) {
                int c = cbase + cc * 32;
                float4 v;
                v.x = sm.xf[qx * 4 + 0][c];
                v.y = sm.xf[qx * 4 + 1][c];
                v.z = sm.xf[qx * 4 + 2][c];
                v.w = sm.xf[qx * 4 + 3][c];
                *(float4*)&out[((size_t)b * 128 + c) * NPIX + tile * 64 + h * 32 + qx * 4] = v;
            }
        }
        __syncthreads();
    }
}

// ---------------------------------------------------------------------------
extern "C" void kernel_launch(void* const* d_in, const int* in_sizes, int n_in,
                              void* d_out, int out_size, void* d_ws, size_t ws_size,
                              hipStream_t stream) {
    const float* x = (const float*)d_in[0];
    const float* ln1_w = (const float*)d_in[1];
    const float* ln1_b = (const float*)d_in[2];
    const float* qkv_w = (const float*)d_in[3];
    const float* qkv_dw = (const float*)d_in[4];
    const float* temperature = (const float*)d_in[5];
    const float* attn_proj = (const float*)d_in[6];
    const float* ln2_w = (const float*)d_in[7];
    const float* ln2_b = (const float*)d_in[8];
    const float* pin_w = (const float*)d_in[9];
    const float* c1_w = (const float*)d_in[10];
    const float* c3_w = (const float*)d_in[11];
    const float* c5_w = (const float*)d_in[12];
    const float* pout_w = (const float*)d_in[13];
    float* out = (float*)d_out;

    char* ws = (char*)d_ws;
    ushort* qkv_pre = (ushort*)(ws + 0);            // 100,663,296 (dead after dwconv3)
    ushort* qkv     = (ushort*)(ws + 100663296);    // 100,663,296 (dead after mv_ln)
    ushort* x2      = (ushort*)(ws + 201326592);    //  33,554,432 px-major (lives to end)
    ushort* t       = (ushort*)(ws + 0);            //  67,108,864 (reuses qkv_pre)
    ushort* gated   = (ushort*)(ws + 67108864);     // 134,217,728 (reuses qkv region)
    ushort* Mb16    = (ushort*)(ws + 235151360);    //    262,144
    ushort* qkv_wb  = (ushort*)(ws + 235413504);    //     98,304
    ushort* pin_wb  = (ushort*)(ws + 235511808);    //     65,536
    ushort* pout_wb = (ushort*)(ws + 235577344);    //    131,072  (end ~235.7 MB)

    // K0: weight conversion (f32 -> bf16)
    wcvt<<<576, 256, 0, stream>>>(qkv_w, qkv_wb, 49152, pin_w, pin_wb, 32768, pout_w, pout_wb, 65536);
    // K1: qkv_pre = qkv_w @ LN1(x)
    ln_gemm_mfma<384><<<2048, 256, 0, stream>>>(x, qkv_wb, ln1_w, ln1_b, qkv_pre);
    // K2: qkv = dwconv3x3(qkv_pre)
    dwconv3_lds<<<dim3(384, 8), 256, 0, stream>>>(qkv_pre, qkv_dw, qkv, 384);
    // K3: attention (norms + QK^T + softmax + attn_proj fold)
    attn_M<<<64, 512, 0, stream>>>(qkv, temperature, attn_proj, Mb16);
    // K4+K5 fused: x2 = x + M_b @ v ; t = pin @ LN2(x2)
    mv_ln_mfma<<<2048, 256, 0, stream>>>(qkv, Mb16, x, pin_wb, ln2_w, ln2_b, x2, t);
    // K6/K7 fused + gating (px-grouped gated output)
    dw_gated<<<dim3(256, 8), 256, 0, stream>>>(t, c3_w, c5_w, c1_w, gated);
    // K8: out = x2 + pout @ gated (tr_read B-frags)
    gdfn_mfma<<<2048, 256, 0, stream>>>(gated, x2, pout_wb, out);
}

// Round 15
// 297.656 us; speedup vs baseline: 1.0581x; 1.0581x over previous
//
#include <hip/hip_runtime.h>
#include <type_traits>

typedef unsigned short ushort;
typedef unsigned int uint;
typedef __bf16 bf16x8 __attribute__((ext_vector_type(8)));
typedef unsigned short ushort8v __attribute__((ext_vector_type(8)));
typedef float f32x4 __attribute__((ext_vector_type(4)));

__device__ __forceinline__ float b2f(ushort u) {
    unsigned int x = ((unsigned int)u) << 16;
    float f;
    __builtin_memcpy(&f, &x, 4);
    return f;
}
__device__ __forceinline__ ushort f2bf(float f) {
    unsigned int x;
    __builtin_memcpy(&x, &f, 4);
    unsigned int r = x + 0x7fffu + ((x >> 16) & 1u);
    return (ushort)(r >> 16);
}
__device__ __forceinline__ float u2f_lo(uint u) {
    uint x = u << 16;
    float f;
    __builtin_memcpy(&f, &x, 4);
    return f;
}
__device__ __forceinline__ float u2f_hi(uint u) {
    uint x = u & 0xffff0000u;
    float f;
    __builtin_memcpy(&f, &x, 4);
    return f;
}
__device__ __forceinline__ uint packbf(float a, float b) {
    return (uint)f2bf(a) | ((uint)f2bf(b) << 16);
}

#define NPIX 16384  // H*W = 128*128
#define PSTRIDE 136 // padded plane row stride (ushorts); 68 uints

// Channel-major tiled layout: [b][tile(256)][ch(CH)][64 px]
__device__ __forceinline__ size_t tadr(int b, int CH, int tile, int ch, int off) {
    return (((size_t)b * 256 + tile) * CH + ch) * 64 + off;
}
// Pixel-major tiled layout for x2: [b][tile(256)][px(64)][ch(128)]
__device__ __forceinline__ size_t padr(int b, int tile, int p, int c) {
    return (((size_t)b * 256 + tile) * 64 + p) * 128 + c;
}

// ---------------------------------------------------------------------------
// stage one 128x128 plane (channel c of ch-major tiled tensor) into padded LDS.
// ---------------------------------------------------------------------------
__device__ __forceinline__ void stage_plane(ushort* pl, const ushort* __restrict__ src,
                                            int b, int c, int CH, int tid) {
    uint* plu = (uint*)pl;
    for (int i = tid; i < 784; i += 256) {
        int idx;
        if (i < 136) idx = i;                       // rows 0-1
        else if (i < 272) idx = 8840 + (i - 136);   // rows 130-131
        else {
            int j = i - 272;
            int r = (j >> 2) + 2;                   // rows 2..129
            int cs = j & 3;
            idx = r * 68 + (cs == 0 ? 0 : 64 + cs); // uint 0 (left pad), 65-67 (right pad)
        }
        plu[idx] = 0u;
    }
    for (int i = tid; i < 2048; i += 256) {
        int row = i >> 4, xg = (i & 15) << 3;
        int px0 = row * 128 + xg;
        uint4 v = *(const uint4*)&src[tadr(b, CH, px0 >> 6, c, px0 & 63)];
        uint* dst = (uint*)&pl[(row + 2) * PSTRIDE + xg + 2];
        dst[0] = v.x; dst[1] = v.y; dst[2] = v.z; dst[3] = v.w;
    }
    __syncthreads();
}

// unpack 12 consecutive bf16 at rowp (16B-aligned) into f32
__device__ __forceinline__ void unpack12(const ushort* rowp, float* cc) {
    const uint* rp = (const uint*)rowp;
    uint4 u = *(const uint4*)rp;
    uint2 v = *(const uint2*)(rp + 4);
    cc[0] = u2f_lo(u.x); cc[1] = u2f_hi(u.x);
    cc[2] = u2f_lo(u.y); cc[3] = u2f_hi(u.y);
    cc[4] = u2f_lo(u.z); cc[5] = u2f_hi(u.z);
    cc[6] = u2f_lo(u.w); cc[7] = u2f_hi(u.w);
    cc[8] = u2f_lo(v.x); cc[9] = u2f_hi(v.x);
    cc[10] = u2f_lo(v.y); cc[11] = u2f_hi(v.y);
}

// ---------------------------------------------------------------------------
// K0: convert fp32 weights to bf16 once (qkv_w, pin_w, pout_w).
// ---------------------------------------------------------------------------
__global__ __launch_bounds__(256) void wcvt(const float* __restrict__ s0, ushort* __restrict__ d0, int n0,
                                            const float* __restrict__ s1, ushort* __restrict__ d1, int n1,
                                            const float* __restrict__ s2, ushort* __restrict__ d2, int n2) {
    int i = blockIdx.x * 256 + threadIdx.x;
    if (i < n0) d0[i] = f2bf(s0[i]);
    else if (i < n0 + n1) d1[i - n0] = f2bf(s1[i - n0]);
    else if (i < n0 + n1 + n2) d2[i - n0 - n1] = f2bf(s2[i - n0 - n1]);
}

// ---------------------------------------------------------------------------
// K1: fused LayerNorm(C=128) + qkv 1x1 conv via MFMA (R12 structure).
// ---------------------------------------------------------------------------
template <int O>
__global__ __launch_bounds__(256) void ln_gemm_mfma(const float* __restrict__ xin,
                                                    const ushort* __restrict__ Wb,
                                                    const float* __restrict__ gamma,
                                                    const float* __restrict__ beta,
                                                    ushort* __restrict__ out) {
    __shared__ ushort xs[64][136];
    __shared__ float red[2][4][64];
    __shared__ float mu[64], rs[64];
    __shared__ float gl[128], bl[128];

    const int blk = blockIdx.x;
    const int b = blk >> 8;
    const int tile = blk & 255;
    const int tid = threadIdx.x;

    const float* xb = xin + (size_t)b * 128 * NPIX + tile * 64;
    float vx[4][8];
#pragma unroll
    for (int k = 0; k < 4; k++) {
        int i = tid + k * 256;
        int p = i & 63, cg = i >> 6;
        const float* src = xb + (size_t)(cg * 8) * NPIX + p;
#pragma unroll
        for (int j = 0; j < 8; j++) vx[k][j] = src[(size_t)j * NPIX];
    }
    if (tid < 128) {
        gl[tid] = gamma[tid];
        bl[tid] = beta[tid];
    }
#pragma unroll
    for (int k = 0; k < 4; k++) {
        int i = tid + k * 256;
        int p = i & 63, cg = i >> 6;
        ushort8v u;
#pragma unroll
        for (int j = 0; j < 8; j++) u[j] = f2bf(vx[k][j]);
        *(ushort8v*)&xs[p][cg * 8] = u;
    }
    __syncthreads();

    {
        const int p = tid & 63, part = tid >> 6;
        float s = 0.f, ss = 0.f;
#pragma unroll
        for (int q = 0; q < 4; q++) {
            ushort8v u = *(const ushort8v*)&xs[p][part * 32 + q * 8];
#pragma unroll
            for (int j = 0; j < 8; j++) {
                float v = b2f(u[j]);
                s += v;
                ss += v * v;
            }
        }
        red[0][part][p] = s;
        red[1][part][p] = ss;
    }
    __syncthreads();
    if (tid < 64) {
        float s = red[0][0][tid] + red[0][1][tid] + red[0][2][tid] + red[0][3][tid];
        float ss = red[1][0][tid] + red[1][1][tid] + red[1][2][tid] + red[1][3][tid];
        float m = s * (1.f / 128.f);
        float var = ss * (1.f / 128.f) - m * m;
        mu[tid] = m;
        rs[tid] = rsqrtf(var + 1e-5f);
    }
    __syncthreads();
    {
        const int p = tid & 63, part = tid >> 6;
        const float mp = mu[p], rp = rs[p];
#pragma unroll
        for (int q = 0; q < 4; q++) {
            int c0 = part * 32 + q * 8;
            ushort8v u = *(const ushort8v*)&xs[p][c0];
            ushort8v o;
#pragma unroll
            for (int j = 0; j < 8; j++) {
                float v = b2f(u[j]);
                o[j] = f2bf((v - mp) * rp * gl[c0 + j] + bl[c0 + j]);
            }
            *(ushort8v*)&xs[p][c0] = o;
        }
    }
    __syncthreads();

    const int wv = tid >> 6, lane = tid & 63;
    const int lr = lane & 15, lg = lane >> 4;

    bf16x8 bfr[4][4];
#pragma unroll
    for (int t = 0; t < 4; t++)
#pragma unroll
        for (int kc = 0; kc < 4; kc++)
            bfr[t][kc] = __builtin_bit_cast(bf16x8, *(const ushort8v*)&xs[t * 16 + lr][kc * 32 + lg * 8]);

    constexpr int MT = O / 64;
    bf16x8 afp[2][4];
#pragma unroll
    for (int kc = 0; kc < 4; kc++)
        afp[0][kc] = __builtin_bit_cast(bf16x8,
            *(const ushort8v*)&Wb[(size_t)(wv * 16 + lr) * 128 + kc * 32 + lg * 8]);

    f32x4 accPair[2][4];
    const int px8 = tid & 7, cb = tid >> 3;
    ushort* outp = out + tadr(b, O, tile, 0, 0);

#pragma unroll
    for (int mt = 0; mt < MT; mt++) {
        if (mt + 1 < MT) {
            const int o0n = ((mt + 1) * 4 + wv) * 16;
#pragma unroll
            for (int kc = 0; kc < 4; kc++)
                afp[(mt + 1) & 1][kc] = __builtin_bit_cast(bf16x8,
                    *(const ushort8v*)&Wb[(size_t)(o0n + lr) * 128 + kc * 32 + lg * 8]);
        }
        f32x4* acc = accPair[mt & 1];
#pragma unroll
        for (int t = 0; t < 4; t++) acc[t] = (f32x4){0.f, 0.f, 0.f, 0.f};
#pragma unroll
        for (int kc = 0; kc < 4; kc++)
#pragma unroll
            for (int t = 0; t < 4; t++)
                acc[t] = __builtin_amdgcn_mfma_f32_16x16x32_bf16(afp[mt & 1][kc], bfr[t][kc], acc[t], 0, 0, 0);

        if (mt & 1) {
            __syncthreads();
#pragma unroll
            for (int h = 0; h < 2; h++) {
                const int lc = h * 64 + wv * 16 + lg * 4;
#pragma unroll
                for (int t = 0; t < 4; t++) {
                    int px = t * 16 + lr;
                    uint2 pk;
                    pk.x = packbf(accPair[h][t][0], accPair[h][t][1]);
                    pk.y = packbf(accPair[h][t][2], accPair[h][t][3]);
                    *(uint2*)&xs[px][lc] = pk;
                }
            }
            __syncthreads();
            const int pairbase = (mt >> 1) * 128;
#pragma unroll
            for (int cc = 0; cc < 4; cc++) {
                int c = cb + cc * 32;
                ushort8v u;
#pragma unroll
                for (int j = 0; j < 8; j++) u[j] = xs[px8 * 8 + j][c];
                *(ushort8v*)&outp[(size_t)(pairbase + c) * 64 + px8 * 8] = u;
            }
        }
    }
}

// ---------------------------------------------------------------------------
// K2: 3x3 depthwise conv, one (b,c) plane per block; ch-major tiled in/out.
// ---------------------------------------------------------------------------
__global__ __launch_bounds__(256) void dwconv3_lds(const ushort* __restrict__ in,
                                                   const float* __restrict__ wdw,
                                                   ushort* __restrict__ out, int CH) {
    __shared__ ushort pl[132 * PSTRIDE];
    const int c = blockIdx.x;
    const int b = blockIdx.y;
    const int tid = threadIdx.x;

    float w[9];
#pragma unroll
    for (int j = 0; j < 9; j++) w[j] = wdw[c * 9 + j];

    stage_plane(pl, in, b, c, CH, tid);

    const int x = (tid & 15) * 8;
    const int ybase = tid >> 4;
#pragma unroll 1
    for (int k = 0; k < 8; k++) {
        const int y = k * 16 + ybase;
        float a[8];
#pragma unroll
        for (int p = 0; p < 8; p++) a[p] = 0.f;
#pragma unroll
        for (int ky = 0; ky < 3; ky++) {
            float cc[12];
            unpack12(&pl[(y + ky + 1) * PSTRIDE + x], cc);
#pragma unroll
            for (int kx = 0; kx < 3; kx++) {
                float wv = w[ky * 3 + kx];
#pragma unroll
                for (int p = 0; p < 8; p++) a[p] += cc[p + kx + 1] * wv;
            }
        }
        const int px0 = (y << 7) + x;
        uint4 o;
        o.x = packbf(a[0], a[1]);
        o.y = packbf(a[2], a[3]);
        o.z = packbf(a[4], a[5]);
        o.w = packbf(a[6], a[7]);
        *(uint4*)&out[tadr(b, CH, px0 >> 6, c, px0 & 63)] = o;
    }
}

// ---------------------------------------------------------------------------
// K6/K7/gating fused: ch-major tiled in/out (REVERTED to tadr stores — the
// px-grouped layout scattered the producer's writes into 16B granules).
// ---------------------------------------------------------------------------
__global__ __launch_bounds__(256) void dw_gated(const ushort* __restrict__ t,
                                                const float* __restrict__ w3_,
                                                const float* __restrict__ w5_,
                                                const float* __restrict__ c1w,
                                                ushort* __restrict__ gated) {
    __shared__ ushort pl[132 * PSTRIDE];
    const int c = blockIdx.x;
    const int b = blockIdx.y;
    const int tid = threadIdx.x;

    float w3[9], w5[25];
#pragma unroll
    for (int j = 0; j < 9; j++) w3[j] = w3_[c * 9 + j];
#pragma unroll
    for (int j = 0; j < 25; j++) w5[j] = w5_[c * 25 + j];
    const float c1v = c1w[c];

    stage_plane(pl, t, b, c, 256, tid);

    const int x = (tid & 15) * 8;
    const int ybase = tid >> 4;
#pragma unroll 1
    for (int k = 0; k < 8; k++) {
        const int y = k * 16 + ybase;
        float a5[8], a3[8], tc[8];
#pragma unroll
        for (int p = 0; p < 8; p++) { a5[p] = 0.f; a3[p] = 0.f; }
#pragma unroll
        for (int ky = 0; ky < 5; ky++) {
            float cc[12];
            unpack12(&pl[(y + ky) * PSTRIDE + x], cc);
#pragma unroll
            for (int kx = 0; kx < 5; kx++) {
                float wv = w5[ky * 5 + kx];
#pragma unroll
                for (int p = 0; p < 8; p++) a5[p] += cc[p + kx] * wv;
            }
            if (ky >= 1 && ky <= 3) {
#pragma unroll
                for (int kx = 0; kx < 3; kx++) {
                    float wv = w3[(ky - 1) * 3 + kx];
#pragma unroll
                    for (int p = 0; p < 8; p++) a3[p] += cc[p + kx + 1] * wv;
                }
            }
            if (ky == 2) {
#pragma unroll
                for (int p = 0; p < 8; p++) tc[p] = cc[p + 2];
            }
        }
        const int px0 = (y << 7) + x;
        uint4 o3, o5;
        float g[8];
#pragma unroll
        for (int p = 0; p < 8; p++) {
            float x1 = tc[p] * c1v;
            g[p] = x1 * __builtin_amdgcn_rcpf(1.f + __expf(-1.702f * x1));
        }
        o3.x = packbf(g[0] * a3[0], g[1] * a3[1]);
        o3.y = packbf(g[2] * a3[2], g[3] * a3[3]);
        o3.z = packbf(g[4] * a3[4], g[5] * a3[5]);
        o3.w = packbf(g[6] * a3[6], g[7] * a3[7]);
        o5.x = packbf(g[0] * a5[0], g[1] * a5[1]);
        o5.y = packbf(g[2] * a5[2], g[3] * a5[3]);
        o5.z = packbf(g[4] * a5[4], g[5] * a5[5]);
        o5.w = packbf(g[6] * a5[6], g[7] * a5[7]);
        *(uint4*)&gated[tadr(b, 512, px0 >> 6, c, px0 & 63)] = o3;
        *(uint4*)&gated[tadr(b, 512, px0 >> 6, 256 + c, px0 & 63)] = o5;
    }
}

// ---------------------------------------------------------------------------
// K3: per (b,h) attention -> M (unchanged).
// ---------------------------------------------------------------------------
__global__ __launch_bounds__(512) void attn_M(const ushort* __restrict__ qkv,
                                              const float* __restrict__ temp,
                                              const float* __restrict__ attn_proj,
                                              ushort* __restrict__ M) {
    __shared__ float Sp[8][16][16];
    __shared__ float QSS[8][16], KSS[8][16];
    __shared__ float A[16][17];

    const int bh = blockIdx.x, b = bh >> 3, h = bh & 7;
    const int tid = threadIdx.x;
    const int w = tid >> 6, lane = tid & 63;
    const int lr = lane & 15, lg = lane >> 4;

    const size_t qbase = (((size_t)b * 256 + w * 32) * 384 + h * 16 + lr) * 64 + lg * 8;
    const size_t kbase = qbase + (size_t)128 * 64;

    f32x4 acc = {0.f, 0.f, 0.f, 0.f};
    f32x4 accq = {0.f, 0.f, 0.f, 0.f};
    f32x4 acck = {0.f, 0.f, 0.f, 0.f};
#pragma unroll 2
    for (int it = 0; it < 64; it++) {
        size_t off = (size_t)(it >> 1) * (384 * 64) + (it & 1) * 32;
        bf16x8 qf = __builtin_bit_cast(bf16x8, *(const ushort8v*)(qkv + qbase + off));
        bf16x8 kf = __builtin_bit_cast(bf16x8, *(const ushort8v*)(qkv + kbase + off));
        acc = __builtin_amdgcn_mfma_f32_16x16x32_bf16(qf, kf, acc, 0, 0, 0);
        accq = __builtin_amdgcn_mfma_f32_16x16x32_bf16(qf, qf, accq, 0, 0, 0);
        acck = __builtin_amdgcn_mfma_f32_16x16x32_bf16(kf, kf, acck, 0, 0, 0);
    }
#pragma unroll
    for (int r = 0; r < 4; r++) Sp[w][lg * 4 + r][lr] = acc[r];
    if (lg == (lr >> 2)) {
        QSS[w][lr] = accq[lr & 3];
        KSS[w][lr] = acck[lr & 3];
    }
    __syncthreads();

    if (tid < 256) {
        const int d = tid >> 4, e = tid & 15;
        float S = 0.f, q2 = 0.f, k2 = 0.f;
#pragma unroll
        for (int s = 0; s < 8; s++) {
            S += Sp[s][d][e];
            q2 += QSS[s][d];
            k2 += KSS[s][e];
        }
        float nq = fmaxf(sqrtf(q2), 1e-12f);
        float nk = fmaxf(sqrtf(k2), 1e-12f);
        float logit = S / (nq * nk) * temp[h];
        float m = logit;
        for (int off = 8; off; off >>= 1) m = fmaxf(m, __shfl_xor(m, off, 64));
        float ex = expf(logit - m);
        float sum = ex;
        for (int off = 8; off; off >>= 1) sum += __shfl_xor(sum, off, 64);
        A[d][e] = ex / sum;
    }
    __syncthreads();

    for (int i = tid; i < 2048; i += 512) {
        int o = i >> 4, ee = i & 15;
        float acc2 = 0.f;
#pragma unroll
        for (int dd = 0; dd < 16; dd++) acc2 += attn_proj[o * 128 + h * 16 + dd] * A[dd][ee];
        M[((size_t)b * 128 + o) * 128 + h * 16 + ee] = f2bf(acc2);
    }
}

// ---------------------------------------------------------------------------
// K4+K5 FUSED: x2 = x + M_b @ v, then t = pin @ LN2(x2) (unchanged).
// ---------------------------------------------------------------------------
__global__ __launch_bounds__(256) void mv_ln_mfma(const ushort* __restrict__ qkv,
                                                  const ushort* __restrict__ Mb16,
                                                  const float* __restrict__ x,
                                                  const ushort* __restrict__ pin_b,
                                                  const float* __restrict__ gamma,
                                                  const float* __restrict__ beta,
                                                  ushort* __restrict__ x2,
                                                  ushort* __restrict__ t_out) {
    __shared__ ushort ts[64][136];
    __shared__ float red[2][4][64];
    __shared__ float mu[64], rs[64];
    __shared__ float gl[128], bl[128];

    const int blk = blockIdx.x;
    const int b = blk >> 8;
    const int tile = blk & 255;
    const int tid = threadIdx.x;
    const int wv = tid >> 6, lane = tid & 63;
    const int lr = lane & 15, lg = lane >> 4;

    const ushort* Mb = Mb16 + (size_t)b * 128 * 128;
    bf16x8 mfr[2][4];
#pragma unroll
    for (int mt = 0; mt < 2; mt++)
#pragma unroll
        for (int kc = 0; kc < 4; kc++)
            mfr[mt][kc] = __builtin_bit_cast(bf16x8,
                *(const ushort8v*)&Mb[(size_t)((wv * 2 + mt) * 16 + lr) * 128 + kc * 32 + lg * 8]);

    const ushort* vb = qkv + tadr(b, 384, tile, 256, 0);
    ushort8v vv[4];
#pragma unroll
    for (int k = 0; k < 4; k++) {
        int idx = tid + k * 256;
        int c = idx & 127, pg = idx >> 7;
        vv[k] = *(const ushort8v*)&vb[c * 64 + pg * 8];
    }
    if (tid < 128) {
        gl[tid] = gamma[tid];
        bl[tid] = beta[tid];
    }
#pragma unroll
    for (int k = 0; k < 4; k++) {
        int idx = tid + k * 256;
        int c = idx & 127, pg = idx >> 7;
#pragma unroll
        for (int j = 0; j < 8; j++) ts[pg * 8 + j][c] = vv[k][j];
    }
    __syncthreads();

    bf16x8 bfr[4][4];
#pragma unroll
    for (int t = 0; t < 4; t++)
#pragma unroll
        for (int kc = 0; kc < 4; kc++)
            bfr[t][kc] = __builtin_bit_cast(bf16x8, *(const ushort8v*)&ts[t * 16 + lr][kc * 32 + lg * 8]);
    __syncthreads();

#pragma unroll
    for (int mt = 0; mt < 2; mt++) {
        const int o0 = (wv * 2 + mt) * 16;
        f32x4 acc[4] = {{0.f, 0.f, 0.f, 0.f}, {0.f, 0.f, 0.f, 0.f}, {0.f, 0.f, 0.f, 0.f}, {0.f, 0.f, 0.f, 0.f}};
#pragma unroll
        for (int kc = 0; kc < 4; kc++)
#pragma unroll
            for (int t = 0; t < 4; t++)
                acc[t] = __builtin_amdgcn_mfma_f32_16x16x32_bf16(mfr[mt][kc], bfr[t][kc], acc[t], 0, 0, 0);
#pragma unroll
        for (int t = 0; t < 4; t++) {
            int px = t * 16 + lr;
            const float* xp = &x[((size_t)b * 128 + o0 + lg * 4) * NPIX + tile * 64 + px];
            uint2 pk;
            pk.x = packbf(xp[0] + acc[t][0], xp[NPIX] + acc[t][1]);
            pk.y = packbf(xp[2 * NPIX] + acc[t][2], xp[3 * NPIX] + acc[t][3]);
            *(uint2*)&ts[px][o0 + lg * 4] = pk;
        }
    }

    bf16x8 pfp[2][4];
#pragma unroll
    for (int kc = 0; kc < 4; kc++)
        pfp[0][kc] = __builtin_bit_cast(bf16x8,
            *(const ushort8v*)&pin_b[(size_t)(wv * 16 + lr) * 128 + kc * 32 + lg * 8]);
    __syncthreads();

#pragma unroll
    for (int k = 0; k < 4; k++) {
        int idx = tid + k * 256;
        int p = idx >> 4, seg = idx & 15;
        uint4 v = *(const uint4*)&ts[p][seg * 8];
        *(uint4*)&x2[padr(b, tile, p, seg * 8)] = v;
    }
    {
        const int p = tid & 63, part = tid >> 6;
        float s = 0.f, ss = 0.f;
#pragma unroll
        for (int q = 0; q < 4; q++) {
            ushort8v u = *(const ushort8v*)&ts[p][part * 32 + q * 8];
#pragma unroll
            for (int j = 0; j < 8; j++) {
                float v = b2f(u[j]);
                s += v;
                ss += v * v;
            }
        }
        red[0][part][p] = s;
        red[1][part][p] = ss;
    }
    __syncthreads();
    if (tid < 64) {
        float s = red[0][0][tid] + red[0][1][tid] + red[0][2][tid] + red[0][3][tid];
        float ss = red[1][0][tid] + red[1][1][tid] + red[1][2][tid] + red[1][3][tid];
        float m = s * (1.f / 128.f);
        float var = ss * (1.f / 128.f) - m * m;
        mu[tid] = m;
        rs[tid] = rsqrtf(var + 1e-5f);
    }
    __syncthreads();
    {
        const int p = tid & 63, part = tid >> 6;
        const float mp = mu[p], rp = rs[p];
#pragma unroll
        for (int q = 0; q < 4; q++) {
            int c0 = part * 32 + q * 8;
            ushort8v u = *(const ushort8v*)&ts[p][c0];
            ushort8v o;
#pragma unroll
            for (int j = 0; j < 8; j++) {
                float v = b2f(u[j]);
                o[j] = f2bf((v - mp) * rp * gl[c0 + j] + bl[c0 + j]);
            }
            *(ushort8v*)&ts[p][c0] = o;
        }
    }
    __syncthreads();

    bf16x8 bfr2[4][4];
#pragma unroll
    for (int t = 0; t < 4; t++)
#pragma unroll
        for (int kc = 0; kc < 4; kc++)
            bfr2[t][kc] = __builtin_bit_cast(bf16x8, *(const ushort8v*)&ts[t * 16 + lr][kc * 32 + lg * 8]);

    f32x4 accPair[2][4];
    const int px8 = tid & 7, cb = tid >> 3;
    ushort* toutp = t_out + tadr(b, 256, tile, 0, 0);

#pragma unroll
    for (int mt = 0; mt < 4; mt++) {
        if (mt + 1 < 4) {
            const int o0n = ((mt + 1) * 4 + wv) * 16;
#pragma unroll
            for (int kc = 0; kc < 4; kc++)
                pfp[(mt + 1) & 1][kc] = __builtin_bit_cast(bf16x8,
                    *(const ushort8v*)&pin_b[(size_t)(o0n + lr) * 128 + kc * 32 + lg * 8]);
        }
        f32x4* acc = accPair[mt & 1];
#pragma unroll
        for (int t = 0; t < 4; t++) acc[t] = (f32x4){0.f, 0.f, 0.f, 0.f};
#pragma unroll
        for (int kc = 0; kc < 4; kc++)
#pragma unroll
            for (int t = 0; t < 4; t++)
                acc[t] = __builtin_amdgcn_mfma_f32_16x16x32_bf16(pfp[mt & 1][kc], bfr2[t][kc], acc[t], 0, 0, 0);

        if (mt & 1) {
            __syncthreads();
#pragma unroll
            for (int h = 0; h < 2; h++) {
                const int lc = h * 64 + wv * 16 + lg * 4;
#pragma unroll
                for (int t = 0; t < 4; t++) {
                    int px = t * 16 + lr;
                    uint2 pk;
                    pk.x = packbf(accPair[h][t][0], accPair[h][t][1]);
                    pk.y = packbf(accPair[h][t][2], accPair[h][t][3]);
                    *(uint2*)&ts[px][lc] = pk;
                }
            }
            __syncthreads();
            const int pairbase = (mt >> 1) * 128;
#pragma unroll
            for (int cc = 0; cc < 4; cc++) {
                int c = cb + cc * 32;
                ushort8v u;
#pragma unroll
                for (int j = 0; j < 8; j++) u[j] = ts[px8 * 8 + j][c];
                *(ushort8v*)&toutp[(size_t)(pairbase + c) * 64 + px8 * 8] = u;
            }
        }
    }
}

// ---------------------------------------------------------------------------
// K8: out = x2 + pout[128,512] @ gated via MFMA.
// gated stays ch-major (tadr): each 64ch x 64px chunk is a contiguous 8KB
// block, so staging is a coalesced 32B/thread memcpy remapped to the
// tr_read-compatible LDS layout [pxq(4), stride 1040][c(64)][pxl(16)]
// (pxq stride padded +32B to spread ds_write banks). T14 dbuf kept;
// B-fragments via ds_read_b64_tr_b16 (validated R14). f32 repack epilogue.
// ---------------------------------------------------------------------------
__global__ __launch_bounds__(256) void gdfn_mfma(const ushort* __restrict__ gated,
                                                 const ushort* __restrict__ x2,
                                                 const ushort* __restrict__ pout_b,
                                                 float* __restrict__ out) {
    __shared__ union {
        ushort gs[2][4160];   // 16640 B: dbuf chunk, [pxq stride 1040][c][pxl]
        float xf[32][129];    // 16512 B: f32 repack (used after K-loop)
    } sm;

    const int blk = blockIdx.x;
    const int b = blk >> 8;
    const int tile = blk & 255;
    const int tid = threadIdx.x;
    const int wv = tid >> 6, lane = tid & 63;
    const int lr = lane & 15, lg = lane >> 4;

    const ushort* gb = gated + tadr(b, 512, tile, 0, 0);
    // staging map: thread tid covers ushorts [tid*16, +16) of the 8KB chunk
    //   -> c = tid>>2, px0 = (tid&3)*16  => pxq = tid&3, pxl 0..15
    const int sdst = (tid & 3) * 1040 + (tid >> 2) * 16;

    // per-lane tr-read base (bytes): lg selects c-octet, lr selects pxl col
    const uint lbase = (uint)(uintptr_t)&sm.gs[0][0] + lg * 256 + lr * 2;

    f32x4 acc[2][4];
#pragma unroll
    for (int mt = 0; mt < 2; mt++)
#pragma unroll
        for (int tt = 0; tt < 4; tt++) acc[mt][tt] = (f32x4){0.f, 0.f, 0.f, 0.f};

    // prologue: stage chunk 0 into buf 0
    {
        uint4 a0 = *(const uint4*)&gb[tid * 16];
        uint4 a1 = *(const uint4*)&gb[tid * 16 + 8];
        *(uint4*)&sm.gs[0][sdst] = a0;
        *(uint4*)&sm.gs[0][sdst + 8] = a1;
    }
    __syncthreads();

#pragma unroll
    for (int kb = 0; kb < 8; kb++) {
        const int cur = kb & 1;

        // T14 issue-early: next chunk's wide loads
        uint4 nA, nB;
        if (kb < 7) {
            nA = *(const uint4*)&gb[(kb + 1) * 4096 + tid * 16];
            nB = *(const uint4*)&gb[(kb + 1) * 4096 + tid * 16 + 8];
        }

        // B-fragments via hardware transpose reads from sm.gs[cur]
        bf16x8 bfrg[4][2];
        {
            const uint la = lbase + cur * 8320;
#pragma unroll
            for (int tt = 0; tt < 4; tt++)
#pragma unroll
                for (int kc = 0; kc < 2; kc++) {
                    uint2 r0, r1;
                    asm volatile("ds_read_b64_tr_b16 %0, %2 offset:%3\n\t"
                                 "ds_read_b64_tr_b16 %1, %2 offset:%4"
                                 : "=&v"(r0), "=&v"(r1)
                                 : "v"(la), "i"(tt * 2080 + kc * 1024), "i"(tt * 2080 + kc * 1024 + 128));
                    uint4 q;
                    q.x = r0.x; q.y = r0.y; q.z = r1.x; q.w = r1.y;
                    bfrg[tt][kc] = __builtin_bit_cast(bf16x8, q);
                }
        }
        asm volatile("s_waitcnt lgkmcnt(0)" ::: "memory");
        __builtin_amdgcn_sched_barrier(0);

#pragma unroll
        for (int mt = 0; mt < 2; mt++) {
            const int o0 = (wv * 2 + mt) * 16;
            bf16x8 afr[2];
#pragma unroll
            for (int kc = 0; kc < 2; kc++)
                afr[kc] = __builtin_bit_cast(bf16x8,
                    *(const ushort8v*)&pout_b[(size_t)(o0 + lr) * 512 + kb * 64 + kc * 32 + lg * 8]);
#pragma unroll
            for (int kc = 0; kc < 2; kc++)
#pragma unroll
                for (int tt = 0; tt < 4; tt++)
                    acc[mt][tt] = __builtin_amdgcn_mfma_f32_16x16x32_bf16(afr[kc], bfrg[tt][kc], acc[mt][tt], 0, 0, 0);
        }

        // T14 write-late: publish next chunk
        if (kb < 7) {
            *(uint4*)&sm.gs[cur ^ 1][sdst] = nA;
            *(uint4*)&sm.gs[cur ^ 1][sdst + 8] = nB;
        }
        __syncthreads();
    }

    // epilogue: add x2, repack via xf[32][129] in two 32-px halves
#pragma unroll
    for (int h = 0; h < 2; h++) {
#pragma unroll
        for (int mt = 0; mt < 2; mt++)
#pragma unroll
            for (int t2 = 0; t2 < 2; t2++) {
                const int tt = h * 2 + t2;
                int o0 = (wv * 2 + mt) * 16 + lg * 4;
                int px = tt * 16 + lr;
                uint2 xw = *(const uint2*)&x2[padr(b, tile, px, o0)];
                sm.xf[px - h * 32][o0 + 0] = u2f_lo(xw.x) + acc[mt][tt][0];
                sm.xf[px - h * 32][o0 + 1] = u2f_hi(xw.x) + acc[mt][tt][1];
                sm.xf[px - h * 32][o0 + 2] = u2f_lo(xw.y) + acc[mt][tt][2];
                sm.xf[px - h * 32][o0 + 3] = u2f_hi(xw.y) + acc[mt][tt][3];
            }
        __syncthreads();
        {
            const int qx = tid & 7;
            const int cbase = tid >> 3;
#pragma unroll
            for (int cc = 0; cc < 4; cc++) {
                int c = cbase + cc * 32;
                float4 v;
                v.x = sm.xf[qx * 4 + 0][c];
                v.y = sm.xf[qx * 4 + 1][c];
                v.z = sm.xf[qx * 4 + 2][c];
                v.w = sm.xf[qx * 4 + 3][c];
                *(float4*)&out[((size_t)b * 128 + c) * NPIX + tile * 64 + h * 32 + qx * 4] = v;
            }
        }
        __syncthreads();
    }
}

// ---------------------------------------------------------------------------
extern "C" void kernel_launch(void* const* d_in, const int* in_sizes, int n_in,
                              void* d_out, int out_size, void* d_ws, size_t ws_size,
                              hipStream_t stream) {
    const float* x = (const float*)d_in[0];
    const float* ln1_w = (const float*)d_in[1];
    const float* ln1_b = (const float*)d_in[2];
    const float* qkv_w = (const float*)d_in[3];
    const float* qkv_dw = (const float*)d_in[4];
    const float* temperature = (const float*)d_in[5];
    const float* attn_proj = (const float*)d_in[6];
    const float* ln2_w = (const float*)d_in[7];
    const float* ln2_b = (const float*)d_in[8];
    const float* pin_w = (const float*)d_in[9];
    const float* c1_w = (const float*)d_in[10];
    const float* c3_w = (const float*)d_in[11];
    const float* c5_w = (const float*)d_in[12];
    const float* pout_w = (const float*)d_in[13];
    float* out = (float*)d_out;

    char* ws = (char*)d_ws;
    ushort* qkv_pre = (ushort*)(ws + 0);            // 100,663,296 (dead after dwconv3)
    ushort* qkv     = (ushort*)(ws + 100663296);    // 100,663,296 (dead after mv_ln)
    ushort* x2      = (ushort*)(ws + 201326592);    //  33,554,432 px-major (lives to end)
    ushort* t       = (ushort*)(ws + 0);            //  67,108,864 (reuses qkv_pre)
    ushort* gated   = (ushort*)(ws + 67108864);     // 134,217,728 (reuses qkv region)
    ushort* Mb16    = (ushort*)(ws + 235151360);    //    262,144
    ushort* qkv_wb  = (ushort*)(ws + 235413504);    //     98,304
    ushort* pin_wb  = (ushort*)(ws + 235511808);    //     65,536
    ushort* pout_wb = (ushort*)(ws + 235577344);    //    131,072  (end ~235.7 MB)

    // K0: weight conversion (f32 -> bf16)
    wcvt<<<576, 256, 0, stream>>>(qkv_w, qkv_wb, 49152, pin_w, pin_wb, 32768, pout_w, pout_wb, 65536);
    // K1: qkv_pre = qkv_w @ LN1(x)
    ln_gemm_mfma<384><<<2048, 256, 0, stream>>>(x, qkv_wb, ln1_w, ln1_b, qkv_pre);
    // K2: qkv = dwconv3x3(qkv_pre)
    dwconv3_lds<<<dim3(384, 8), 256, 0, stream>>>(qkv_pre, qkv_dw, qkv, 384);
    // K3: attention (norms + QK^T + softmax + attn_proj fold)
    attn_M<<<64, 512, 0, stream>>>(qkv, temperature, attn_proj, Mb16);
    // K4+K5 fused: x2 = x + M_b @ v ; t = pin @ LN2(x2)
    mv_ln_mfma<<<2048, 256, 0, stream>>>(qkv, Mb16, x, pin_wb, ln2_w, ln2_b, x2, t);
    // K6/K7 fused + gating (ch-major tadr output restored)
    dw_gated<<<dim3(256, 8), 256, 0, stream>>>(t, c3_w, c5_w, c1_w, gated);
    // K8: out = x2 + pout @ gated (coalesced staging + tr_read B-frags)
    gdfn_mfma<<<2048, 256, 0, stream>>>(gated, x2, pout_wb, out);
}